// Round 7
// baseline (492.716 us; speedup 1.0000x reference)
//
#include <hip/hip_runtime.h>

#define B_   128
#define L_   196
#define C_   2048
#define H_   512
#define D_   1024
#define CT   128          // channels (N) per block
#define NITER 14          // 2 hchunks (256 H-rows) x 7 K-slices (K=32)
#define RSE  224          // att_s row stride in bf16 elems (448B)

typedef __bf16 bf16x8 __attribute__((ext_vector_type(8)));
typedef float  f32x4  __attribute__((ext_vector_type(4)));

// ---------------- fused prep: Wc->fragment-packed bf16  +  ph = h@Wh + bh + bc ----------------
// wcb3: grp = (((kk*32 + rb)*4 + g)*16 + m); wcb3[grp*8 + j] = Wc[k=kk*32+g*8+j][h=rb*16+m]
// => A-frag (kk, rb) is 1KB contiguous; lane 16g+m reads 16B at +lane*16.
__global__ __launch_bounds__(512) void k_prep(const float* __restrict__ Wc, __bf16* __restrict__ wcb3,
                                              const float* __restrict__ h, const float* __restrict__ Wh,
                                              const float* __restrict__ bh, const float* __restrict__ bc,
                                              float* __restrict__ ph_ws) {
    __shared__ float hs[4][D_];
    const int bid = blockIdx.x, t = threadIdx.x;
    if (bid < 28) {                               // ---- Wc fragment packing: 28*512 = 14336 groups
        int grp = bid * 512 + t;
        int m  = grp & 15;
        int g  = (grp >> 4) & 3;
        int rb = (grp >> 6) & 31;
        int kk = grp >> 11;                       // 0..6
        int hh = rb * 16 + m;
        bf16x8 v;
#pragma unroll
        for (int j = 0; j < 8; ++j) {
            int k = kk * 32 + g * 8 + j;
            v[j] = (k < L_) ? (__bf16)Wc[(size_t)k * H_ + hh] : (__bf16)0.0f;
        }
        *(bf16x8*)&wcb3[(size_t)grp * 8] = v;
    } else {                                      // ---- ph: 32 blocks x 4 batches
        int b0 = (bid - 28) * 4;
        for (int idx = t; idx < 4 * D_; idx += 512)
            hs[idx >> 10][idx & (D_ - 1)] = h[(size_t)(b0 + (idx >> 10)) * D_ + (idx & (D_ - 1))];
        __syncthreads();
        float base = bh[t] + bc[t];
        float a0 = base, a1 = base, a2 = base, a3 = base;
#pragma unroll 8
        for (int d = 0; d < D_; ++d) {
            float wv = Wh[(size_t)d * H_ + t];
            a0 += hs[0][d] * wv; a1 += hs[1][d] * wv; a2 += hs[2][d] * wv; a3 += hs[3][d] * wv;
        }
        ph_ws[(size_t)(b0 + 0) * H_ + t] = a0;
        ph_ws[(size_t)(b0 + 1) * H_ + t] = a1;
        ph_ws[(size_t)(b0 + 2) * H_ + t] = a2;
        ph_ws[(size_t)(b0 + 3) * H_ + t] = a3;
    }
}

__device__ __forceinline__ float fast_tanh(float x) {
    // |x| bounded (~30) here; no clamp needed. tanh(x) = 1 - 2/(exp(2x)+1)
    float e = __builtin_amdgcn_exp2f(x * 2.8853900817779268f);
    return fmaf(-2.0f, __builtin_amdgcn_rcpf(e + 1.0f), 1.0f);
}

// raw barrier: publish ds_writes without draining vmcnt (keeps prefetches in flight)
__device__ __forceinline__ void block_sync_lds() {
    asm volatile("s_waitcnt lgkmcnt(0)" ::: "memory");
    __builtin_amdgcn_sched_barrier(0);
    __builtin_amdgcn_s_barrier();
    __builtin_amdgcn_sched_barrier(0);
}

// ---------------- scores[b][c] = wa . tanh(Wc^T @ att_b + ph) ----------------
// att_s: [128 c][7 slices][4 slots of 16B]; physical slot p = s ^ ((c>>1)&3)
// (write: 64 lanes -> 8 lanes/bank-quad = b128 floor; read: same. Verified by enumeration.)
// 2-deep staging pipeline: iter it issues loads for slice it+2 (svA/svB parity),
// writes slice it+1 from regs loaded one full iteration earlier.
__global__ __launch_bounds__(512, 4) void k_scores(const float* __restrict__ att, const __bf16* __restrict__ wcb3,
                                                   const float* __restrict__ ph_ws, const float* __restrict__ wa,
                                                   const float* __restrict__ ba, float* __restrict__ scores) {
    __shared__ __bf16 att_s[CT * RSE];          // 57,344 B
    __shared__ float  sred[8][4][16];           // 2 KB

    const int t = threadIdx.x, lane = t & 63, wid = t >> 6;
    const int wm = wid >> 1, wn = wid & 1;      // 4 m-waves x 2 n-waves; wave tile 64x64
    const int ct = blockIdx.x, b = blockIdx.y;
    const float* attb = att + ((size_t)b * L_) * C_ + ct * CT;

    // staging role: one channel per thread, one 8-l slot
    const int sc = t & 127, sl = t >> 7;                 // c 0..127, slot 0..3
    const int spdst = sc * RSE + (sl ^ ((sc >> 1) & 3)) * 8;   // + kk*32

    // B-frag addressing
    const int n_ = lane & 15, g_ = lane >> 4;
    const int bbase = (wn * 64 + n_) * RSE + (g_ ^ ((n_ >> 1) & 3)) * 8;   // + nf*16*RSE + kk*32

    const __bf16* apA = wcb3 + (size_t)lane * 8;

    float svA[8], svB[8];
    bf16x8 afr[4];

    // ---- helpers ----
    auto STAGE_LOAD = [&](float (&buf)[8], int kk) {
#pragma unroll
        for (int j = 0; j < 8; ++j) {
            int l = kk * 32 + sl * 8 + j;
            buf[j] = (l < L_) ? attb[(size_t)l * C_ + sc] : 0.0f;
        }
    };
    auto STAGE_WRITE = [&](float (&buf)[8], int kk) {
        bf16x8 r;
#pragma unroll
        for (int j = 0; j < 8; ++j) r[j] = (__bf16)buf[j];
        *(bf16x8*)&att_s[spdst + kk * 32] = r;
    };
    auto ALOAD = [&](int it) {
        int hc = (it >= 7) ? 1 : 0;
        int kk = it - hc * 7;
#pragma unroll
        for (int mf = 0; mf < 4; ++mf)
            afr[mf] = *(const bf16x8*)(apA + (size_t)(kk * 32 + hc * 16 + wm * 4 + mf) * 512);
    };

    // ---- prologue: slice 0 ready, slice-1 loads in flight, first A-frags ----
    STAGE_LOAD(svA, 0);
    ALOAD(0);
    STAGE_LOAD(svB, 1);        // issued before slice-0 cvt -> one-iteration depth from the start
    STAGE_WRITE(svA, 0);
    block_sync_lds();

    f32x4 zero4 = {0.f, 0.f, 0.f, 0.f};
    f32x4 acc[4][4];
#pragma unroll
    for (int mf = 0; mf < 4; ++mf)
#pragma unroll
        for (int nf = 0; nf < 4; ++nf) acc[mf][nf] = zero4;
    float spart[4] = {0.f, 0.f, 0.f, 0.f};

#pragma unroll
    for (int it = 0; it < NITER; ++it) {
        const int hc = (it >= 7) ? 1 : 0;
        const int kk = it - hc * 7;

        // issue loads for slice it+2 (2-deep): buf parity = slice parity (even->A, odd->B)
        if (it <= 4) {
            if ((it & 1) == 0) STAGE_LOAD(svA, it + 2);
            else               STAGE_LOAD(svB, it + 2);
        }

        __builtin_amdgcn_s_setprio(1);
#pragma unroll
        for (int nf = 0; nf < 4; ++nf) {
            bf16x8 bfr = *(const bf16x8*)&att_s[bbase + nf * 16 * RSE + kk * 32];
#pragma unroll
            for (int mf = 0; mf < 4; ++mf)
                acc[mf][nf] = __builtin_amdgcn_mfma_f32_16x16x32_bf16(afr[mf], bfr, acc[mf][nf], 0, 0, 0);
        }
        __builtin_amdgcn_s_setprio(0);

        if (it + 1 < NITER) ALOAD(it + 1);       // refill afr after last use (L2-hit latency hidden)

        // write slice it+1 from regs loaded at iter it-1 (full-iteration vmcnt slack)
        if (it <= 5) {
            if ((it & 1) == 0) STAGE_WRITE(svB, it + 1);
            else               STAGE_WRITE(svA, it + 1);
        }

        if (kk == 6) {   // end of 256-row H-chunk: tanh + wa reduce, reset acc (barrier-free zone)
            const int rbase = hc * 256 + wm * 64 + g_ * 4;
#pragma unroll
            for (int mf = 0; mf < 4; ++mf) {
                const int row = rbase + mf * 16;
                f32x4 phv = *(const f32x4*)&ph_ws[(size_t)b * H_ + row];
                f32x4 wav = *(const f32x4*)&wa[row];
#pragma unroll
                for (int nf = 0; nf < 4; ++nf) {
                    f32x4 tv = acc[mf][nf];
                    float ss = 0.f;
#pragma unroll
                    for (int r = 0; r < 4; ++r)
                        ss += fast_tanh(tv[r] + phv[r]) * wav[r];   // C/D: col=lane&15, row=g_*4+r
                    spart[nf] += ss;
                    acc[mf][nf] = zero4;
                }
            }
        }

        if (it <= 5) block_sync_lds();           // publish slice it+1 (lgkm only, vmcnt untouched)
    }

    // reduce over k-quarters (g_), then across the 4 m-waves via LDS
#pragma unroll
    for (int nf = 0; nf < 4; ++nf) {
        spart[nf] += __shfl_xor(spart[nf], 16);
        spart[nf] += __shfl_xor(spart[nf], 32);
    }
    if (g_ == 0) {
#pragma unroll
        for (int nf = 0; nf < 4; ++nf) sred[wid][nf][n_] = spart[nf];
    }
    __syncthreads();
    if (wid < 2 && g_ == 0) {                    // wid acts as wn
        const float ba0 = ba[0];
#pragma unroll
        for (int nf = 0; nf < 4; ++nf) {
            float v = ba0;
#pragma unroll
            for (int wmm = 0; wmm < 4; ++wmm) v += sred[wmm * 2 + wid][nf][n_];
            scores[(size_t)b * C_ + ct * CT + wid * 64 + nf * 16 + n_] = v;
        }
    }
}

// ---------------- fused: softmax over C  +  weighted[b][l] = sum_c w[c]*att[b][l][c] ----------------
__global__ __launch_bounds__(512) void k_fused(const float* __restrict__ att, const float* __restrict__ sc,
                                               float* __restrict__ out) {
    __shared__ float w_s[C_];
    __shared__ float red[8], red2[8];
    const int b = blockIdx.y, q = blockIdx.x;       // q: l-quarter 0..3
    const int t = threadIdx.x;
    const int lane = t & 63, wid = t >> 6;

    const float* sp = sc + (size_t)b * C_;
    float v[4];
#pragma unroll
    for (int j = 0; j < 4; ++j) v[j] = sp[j * 512 + t];
    float m = fmaxf(fmaxf(v[0], v[1]), fmaxf(v[2], v[3]));
#pragma unroll
    for (int off = 32; off >= 1; off >>= 1) m = fmaxf(m, __shfl_xor(m, off));
    if (lane == 0) red[wid] = m;
    __syncthreads();
#pragma unroll
    for (int w = 0; w < 8; ++w) m = fmaxf(m, red[w]);
    float s = 0.f;
#pragma unroll
    for (int j = 0; j < 4; ++j) {
        v[j] = __builtin_amdgcn_exp2f((v[j] - m) * 1.4426950408889634f);
        s += v[j];
    }
#pragma unroll
    for (int off = 32; off >= 1; off >>= 1) s += __shfl_xor(s, off);
    if (lane == 0) red2[wid] = s;
    __syncthreads();
    s = 0.f;
#pragma unroll
    for (int w = 0; w < 8; ++w) s += red2[w];
    float inv = 1.0f / s;
    float* wout = out + B_ * L_;
#pragma unroll
    for (int j = 0; j < 4; ++j) {
        float wv = v[j] * inv;
        w_s[j * 512 + t] = wv;
        if (q == 0) wout[(size_t)b * C_ + j * 512 + t] = wv;
    }
    __syncthreads();

    // weighted: 2 rows per wave concurrently for ILP
    for (int l0 = wid; l0 < 49; l0 += 16) {
        const int l1 = l0 + 8;
        const bool has1 = (l1 < 49);
        const float* ap0 = att + ((size_t)b * L_ + (q * 49 + l0)) * C_;
        const float* ap1 = att + ((size_t)b * L_ + (q * 49 + (has1 ? l1 : l0))) * C_;
        float a0 = 0.f, a1 = 0.f;
#pragma unroll
        for (int j = 0; j < 8; ++j) {
            int c = j * 256 + lane * 4;
            f32x4 x0 = *(const f32x4*)(ap0 + c);
            f32x4 x1 = *(const f32x4*)(ap1 + c);
            f32x4 w4 = *(const f32x4*)&w_s[c];
            a0 += x0[0] * w4[0] + x0[1] * w4[1] + x0[2] * w4[2] + x0[3] * w4[3];
            a1 += x1[0] * w4[0] + x1[1] * w4[1] + x1[2] * w4[2] + x1[3] * w4[3];
        }
#pragma unroll
        for (int off = 32; off >= 1; off >>= 1) {
            a0 += __shfl_xor(a0, off);
            a1 += __shfl_xor(a1, off);
        }
        if (lane == 0) {
            out[(size_t)b * L_ + q * 49 + l0] = a0;
            if (has1) out[(size_t)b * L_ + q * 49 + l1] = a1;
        }
    }
}

extern "C" void kernel_launch(void* const* d_in, const int* in_sizes, int n_in,
                              void* d_out, int out_size, void* d_ws, size_t ws_size,
                              hipStream_t stream) {
    const float* att = (const float*)d_in[0];
    const float* h   = (const float*)d_in[1];
    const float* Wc  = (const float*)d_in[2];
    const float* bc  = (const float*)d_in[3];
    const float* Wh  = (const float*)d_in[4];
    const float* bh  = (const float*)d_in[5];
    const float* wa  = (const float*)d_in[6];
    const float* ba  = (const float*)d_in[7];
    float* out = (float*)d_out;

    // workspace: ph (128*512 f32) | scores (128*2048 f32) | wcb3 (512*224 bf16)
    float* ph_ws  = (float*)d_ws;
    float* scores = ph_ws + B_ * H_;
    __bf16* wcb3  = (__bf16*)(scores + (size_t)B_ * C_);

    k_prep  <<<dim3(60), 512, 0, stream>>>(Wc, wcb3, h, Wh, bh, bc, ph_ws);
    k_scores<<<dim3(C_ / CT, B_), 512, 0, stream>>>(att, wcb3, ph_ws, wa, ba, scores);
    k_fused <<<dim3(4, B_), 512, 0, stream>>>(att, scores, out);
}